// Round 1
// baseline (309.671 us; speedup 1.0000x reference)
//
#include <hip/hip_runtime.h>
#include <hip/hip_bf16.h>
#include <cstdint>

// ---------- types ----------
typedef short bf16x8 __attribute__((ext_vector_type(8)));   // 8 bf16 = 4 VGPRs (MFMA A/B frag)
typedef float f32x4  __attribute__((ext_vector_type(4)));   // MFMA C/D frag
typedef short bvec8  __attribute__((ext_vector_type(8)));   // 16B load/store
typedef short bvec4  __attribute__((ext_vector_type(4)));   // 8B store

#define D_MODEL 512
#define SEQ     4096
#define NHEADS  8
#define DFF     2048
#define MROWS   8192   // B*S = 2*4096

#define LSTR 72        // padded LDS row stride in bf16 elems (64 + 8)

__device__ inline short f2b(float f) {
    union { float f; uint32_t u; } c; c.f = f;
    uint32_t u = c.u;
    u += 0x7fffu + ((u >> 16) & 1u);   // round-to-nearest-even
    return (short)(u >> 16);
}

// ---------- cast x fp32 -> bf16 ----------
__global__ void cast_f32_bf16(const float* __restrict__ in, short* __restrict__ out, int n8) {
    int i = blockIdx.x * blockDim.x + threadIdx.x;
    if (i >= n8) return;
    const float4* p = (const float4*)in + (size_t)i * 2;
    float4 a = p[0], b = p[1];
    bvec8 o = { f2b(a.x), f2b(a.y), f2b(a.z), f2b(a.w),
                f2b(b.x), f2b(b.y), f2b(b.z), f2b(b.w) };
    ((bvec8*)out)[i] = o;
}

// ---------- W [K][N] fp32 -> Wt [N][K] bf16 ----------
__global__ void transpose_cast(const float* __restrict__ W, short* __restrict__ Wt, int K, int N) {
    __shared__ float tile[64][65];
    int k0 = blockIdx.x * 64;
    int n0 = blockIdx.y * 64;
    #pragma unroll
    for (int i = 0; i < 16; ++i) {
        int idx = i * 256 + threadIdx.x;
        int r = idx >> 6, c = idx & 63;
        tile[r][c] = W[(size_t)(k0 + r) * N + n0 + c];
    }
    __syncthreads();
    #pragma unroll
    for (int i = 0; i < 16; ++i) {
        int idx = i * 256 + threadIdx.x;
        int r = idx >> 6, c = idx & 63;          // r along N, c along K
        Wt[(size_t)(n0 + r) * K + k0 + c] = f2b(tile[c][r]);
    }
}

// ---------- GEMM: C = A[M,K] * Bt[N,K]^T, bf16 MFMA, fp32 acc ----------
// EPI 0: bf16 out, head layout [B,H,S,64]          (Q, K projections)
// EPI 1: bf16 out, head-transposed [B,H,64,S]      (V projection)
// EPI 2: fp32 out = acc + bias[n] + res[m*N+n]     (dense, ff2)
// EPI 3: bf16 out = relu(acc + bias[n]) row-major  (ff1)
template<int EPI>
__global__ __launch_bounds__(256, 2)
void gemm_bt(const short* __restrict__ A, const short* __restrict__ Bt,
             int M, int N, int K,
             const float* __restrict__ bias, const float* __restrict__ res,
             void* __restrict__ out) {
    __shared__ short a_lds[128 * LSTR];
    __shared__ short b_lds[128 * LSTR];
    const int tid  = threadIdx.x;
    const int lane = tid & 63;
    const int w    = tid >> 6;
    const int wm   = w >> 1, wn = w & 1;
    const int m0 = blockIdx.y * 128, n0 = blockIdx.x * 128;

    f32x4 acc[4][4];
    #pragma unroll
    for (int i = 0; i < 4; ++i)
        #pragma unroll
        for (int j = 0; j < 4; ++j) acc[i][j] = (f32x4){0.f, 0.f, 0.f, 0.f};

    const int lrow = lane & 15;
    const int lk8  = (lane >> 4) * 8;

    for (int kt = 0; kt < K; kt += 64) {
        #pragma unroll
        for (int s = 0; s < 4; ++s) {
            int chunk = s * 256 + tid;        // 0..1023
            int row = chunk >> 3;             // 0..127
            int col = (chunk & 7) * 8;        // 0..56
            *(bvec8*)&a_lds[row * LSTR + col] =
                *(const bvec8*)&A[(size_t)(m0 + row) * K + kt + col];
            *(bvec8*)&b_lds[row * LSTR + col] =
                *(const bvec8*)&Bt[(size_t)(n0 + row) * K + kt + col];
        }
        __syncthreads();
        #pragma unroll
        for (int kk = 0; kk < 2; ++kk) {
            bf16x8 af[4], bfr[4];
            #pragma unroll
            for (int i = 0; i < 4; ++i)
                af[i] = *(const bf16x8*)&a_lds[(wm * 64 + i * 16 + lrow) * LSTR + kk * 32 + lk8];
            #pragma unroll
            for (int j = 0; j < 4; ++j)
                bfr[j] = *(const bf16x8*)&b_lds[(wn * 64 + j * 16 + lrow) * LSTR + kk * 32 + lk8];
            #pragma unroll
            for (int i = 0; i < 4; ++i)
                #pragma unroll
                for (int j = 0; j < 4; ++j)
                    acc[i][j] = __builtin_amdgcn_mfma_f32_16x16x32_bf16(af[i], bfr[j], acc[i][j], 0, 0, 0);
        }
        __syncthreads();
    }

    #pragma unroll
    for (int i = 0; i < 4; ++i) {
        #pragma unroll
        for (int j = 0; j < 4; ++j) {
            #pragma unroll
            for (int r = 0; r < 4; ++r) {
                int m = m0 + wm * 64 + i * 16 + (lane >> 4) * 4 + r;
                int n = n0 + wn * 64 + j * 16 + (lane & 15);
                float v = acc[i][j][r];
                if constexpr (EPI == 0) {
                    int b = m >> 12, s = m & 4095, h = n >> 6, dp = n & 63;
                    ((short*)out)[(((size_t)(b * NHEADS + h)) * SEQ + s) * 64 + dp] = f2b(v);
                } else if constexpr (EPI == 1) {
                    int b = m >> 12, s = m & 4095, h = n >> 6, dp = n & 63;
                    ((short*)out)[(((size_t)(b * NHEADS + h)) * 64 + dp) * SEQ + s] = f2b(v);
                } else if constexpr (EPI == 2) {
                    ((float*)out)[(size_t)m * N + n] = v + bias[n] + res[(size_t)m * N + n];
                } else {
                    float t = v + bias[n];
                    ((short*)out)[(size_t)m * N + n] = f2b(t > 0.f ? t : 0.f);
                }
            }
        }
    }
}

// ---------- sigmoid attention: ctx[b,s,h*64+dp] = sum_k sigmoid(q.k/8 + bias) * v ----------
__global__ __launch_bounds__(256, 2)
void attn_kernel(const short* __restrict__ Q, const short* __restrict__ Kb,
                 const short* __restrict__ VT, short* __restrict__ ctx) {
    __shared__ short qs[64 * LSTR];
    __shared__ short ks[64 * LSTR];
    __shared__ short vs[64 * LSTR];
    __shared__ short ps[4][16 * LSTR];

    const int tid  = threadIdx.x;
    const int lane = tid & 63;
    const int w    = tid >> 6;
    const int bh   = blockIdx.y;
    const int q0   = blockIdx.x * 64;
    const size_t base = (size_t)bh * SEQ * 64;

    #pragma unroll
    for (int s = 0; s < 2; ++s) {
        int chunk = s * 256 + tid;      // 0..511
        int row = chunk >> 3;
        int col = (chunk & 7) * 8;
        *(bvec8*)&qs[row * LSTR + col] = *(const bvec8*)&Q[base + (size_t)(q0 + row) * 64 + col];
    }
    __syncthreads();

    const int lrow = lane & 15;
    const int lk8  = (lane >> 4) * 8;
    bf16x8 qf[2];
    #pragma unroll
    for (int kk = 0; kk < 2; ++kk)
        qf[kk] = *(const bf16x8*)&qs[(w * 16 + lrow) * LSTR + kk * 32 + lk8];

    f32x4 oacc[4];
    #pragma unroll
    for (int j = 0; j < 4; ++j) oacc[j] = (f32x4){0.f, 0.f, 0.f, 0.f};

    const float BIAS  = -8.317766166719343f;  // -log(4096)
    const float SCALE = 0.125f;               // 1/sqrt(64)

    for (int kt = 0; kt < SEQ; kt += 64) {
        __syncthreads();
        #pragma unroll
        for (int s = 0; s < 2; ++s) {
            int chunk = s * 256 + tid;
            int row = chunk >> 3;
            int col = (chunk & 7) * 8;
            *(bvec8*)&ks[row * LSTR + col] = *(const bvec8*)&Kb[base + (size_t)(kt + row) * 64 + col];
            *(bvec8*)&vs[row * LSTR + col] = *(const bvec8*)&VT[base + (size_t)row * SEQ + kt + col];
        }
        __syncthreads();

        // S = Q K^T (per wave: 16 q-rows x 64 keys), sigmoid -> P (bf16, LDS)
        #pragma unroll
        for (int kb = 0; kb < 4; ++kb) {
            f32x4 sacc = (f32x4){0.f, 0.f, 0.f, 0.f};
            #pragma unroll
            for (int kk = 0; kk < 2; ++kk) {
                bf16x8 kf = *(const bf16x8*)&ks[(kb * 16 + lrow) * LSTR + kk * 32 + lk8];
                sacc = __builtin_amdgcn_mfma_f32_16x16x32_bf16(qf[kk], kf, sacc, 0, 0, 0);
            }
            #pragma unroll
            for (int r = 0; r < 4; ++r) {
                float z = sacc[r] * SCALE + BIAS;
                float p = __builtin_amdgcn_rcpf(1.f + __expf(-z));
                ps[w][((lane >> 4) * 4 + r) * LSTR + kb * 16 + (lane & 15)] = f2b(p);
            }
        }
        // O += P V  (wave-local P; LDS ordering within wave handled by compiler waits)
        bf16x8 pf[2];
        #pragma unroll
        for (int kk = 0; kk < 2; ++kk)
            pf[kk] = *(const bf16x8*)&ps[w][lrow * LSTR + kk * 32 + lk8];
        #pragma unroll
        for (int dj = 0; dj < 4; ++dj) {
            #pragma unroll
            for (int kk = 0; kk < 2; ++kk) {
                bf16x8 vf = *(const bf16x8*)&vs[(dj * 16 + lrow) * LSTR + kk * 32 + lk8];
                oacc[dj] = __builtin_amdgcn_mfma_f32_16x16x32_bf16(pf[kk], vf, oacc[dj], 0, 0, 0);
            }
        }
    }

    const int b = bh >> 3, h = bh & 7;
    #pragma unroll
    for (int dj = 0; dj < 4; ++dj) {
        #pragma unroll
        for (int r = 0; r < 4; ++r) {
            int qrow = q0 + w * 16 + (lane >> 4) * 4 + r;
            int dp   = dj * 16 + (lane & 15);
            ctx[((size_t)(b * SEQ + qrow)) * D_MODEL + h * 64 + dp] = f2b(oacc[dj][r]);
        }
    }
}

// ---------- LayerNorm: one wave per 512-elem row ----------
template<bool WRITE_BF16>
__global__ void ln_kernel(const float* __restrict__ in, const float* __restrict__ g,
                          const float* __restrict__ b, float* __restrict__ outf,
                          short* __restrict__ outb) {
    int row  = blockIdx.x * 4 + (threadIdx.x >> 6);
    int lane = threadIdx.x & 63;
    const float4* p = (const float4*)(in + (size_t)row * D_MODEL);
    float4 v0 = p[lane], v1 = p[lane + 64];
    float sum = v0.x + v0.y + v0.z + v0.w + v1.x + v1.y + v1.z + v1.w;
    #pragma unroll
    for (int o = 1; o < 64; o <<= 1) sum += __shfl_xor(sum, o, 64);
    float mu = sum * (1.f / 512.f);
    float d0 = v0.x - mu, d1 = v0.y - mu, d2 = v0.z - mu, d3 = v0.w - mu;
    float d4 = v1.x - mu, d5 = v1.y - mu, d6 = v1.z - mu, d7 = v1.w - mu;
    float sq = d0*d0 + d1*d1 + d2*d2 + d3*d3 + d4*d4 + d5*d5 + d6*d6 + d7*d7;
    #pragma unroll
    for (int o = 1; o < 64; o <<= 1) sq += __shfl_xor(sq, o, 64);
    float rs = rsqrtf(sq * (1.f / 512.f) + 1e-5f);
    const float4* gp = (const float4*)g;
    const float4* bp = (const float4*)b;
    float4 g0 = gp[lane], g1 = gp[lane + 64];
    float4 b0 = bp[lane], b1 = bp[lane + 64];
    float4 y0, y1;
    y0.x = d0 * rs * g0.x + b0.x;  y0.y = d1 * rs * g0.y + b0.y;
    y0.z = d2 * rs * g0.z + b0.z;  y0.w = d3 * rs * g0.w + b0.w;
    y1.x = d4 * rs * g1.x + b1.x;  y1.y = d5 * rs * g1.y + b1.y;
    y1.z = d6 * rs * g1.z + b1.z;  y1.w = d7 * rs * g1.w + b1.w;
    float4* q = (float4*)(outf + (size_t)row * D_MODEL);
    q[lane] = y0;  q[lane + 64] = y1;
    if constexpr (WRITE_BF16) {
        bvec4 o0 = { f2b(y0.x), f2b(y0.y), f2b(y0.z), f2b(y0.w) };
        bvec4 o1 = { f2b(y1.x), f2b(y1.y), f2b(y1.z), f2b(y1.w) };
        *(bvec4*)(outb + (size_t)row * D_MODEL + lane * 4)       = o0;
        *(bvec4*)(outb + (size_t)row * D_MODEL + 256 + lane * 4) = o1;
    }
}

// ---------- launch ----------
extern "C" void kernel_launch(void* const* d_in, const int* in_sizes, int n_in,
                              void* d_out, int out_size, void* d_ws, size_t ws_size,
                              hipStream_t stream) {
    const float* x       = (const float*)d_in[0];
    const float* Wq      = (const float*)d_in[1];
    const float* Wk      = (const float*)d_in[2];
    const float* Wv      = (const float*)d_in[3];
    const float* dense_w = (const float*)d_in[4];
    const float* dense_b = (const float*)d_in[5];
    const float* ff1_w   = (const float*)d_in[6];
    const float* ff1_b   = (const float*)d_in[7];
    const float* ff2_w   = (const float*)d_in[8];
    const float* ff2_b   = (const float*)d_in[9];
    const float* ln1_g   = (const float*)d_in[10];
    const float* ln1_b   = (const float*)d_in[11];
    const float* ln2_g   = (const float*)d_in[12];
    const float* ln2_b   = (const float*)d_in[13];

    char* ws = (char*)d_ws;
    short* xb   = (short*)(ws + 0);            // 8,388,608 B ; reused as ctx after attention
    short* wqT  = (short*)(ws + 8388608);      // 524,288 each
    short* wkT  = (short*)(ws + 8912896);
    short* wvT  = (short*)(ws + 9437184);
    short* wdT  = (short*)(ws + 9961472);
    short* f1T  = (short*)(ws + 10485760);     // 2,097,152
    short* f2T  = (short*)(ws + 12582912);     // 2,097,152
    short* qb   = (short*)(ws + 14680064);     // 8,388,608
    short* kb   = (short*)(ws + 23068672);     // 8,388,608
    short* vtb  = (short*)(ws + 31457280);     // 8,388,608
    short* hb   = (short*)(ws + 14680064);     // 33,554,432 (overlays q/k/vt, dead by then)
    float* t1   = (float*)(ws + 48234496);     // 16,777,216 ; also x1f and t2 (in-place)
    short* x1b  = (short*)(ws + 65011712);     // 8,388,608
    short* ctx  = xb;
    float* x1f  = t1;

    // casts / transposes
    cast_f32_bf16<<<2048, 256, 0, stream>>>(x, xb, MROWS * D_MODEL / 8);
    transpose_cast<<<dim3(8, 8),  256, 0, stream>>>(Wq,      wqT, 512, 512);
    transpose_cast<<<dim3(8, 8),  256, 0, stream>>>(Wk,      wkT, 512, 512);
    transpose_cast<<<dim3(8, 8),  256, 0, stream>>>(Wv,      wvT, 512, 512);
    transpose_cast<<<dim3(8, 8),  256, 0, stream>>>(dense_w, wdT, 512, 512);
    transpose_cast<<<dim3(8, 32), 256, 0, stream>>>(ff1_w,   f1T, 512, 2048);
    transpose_cast<<<dim3(32, 8), 256, 0, stream>>>(ff2_w,   f2T, 2048, 512);

    // projections
    gemm_bt<0><<<dim3(4, 64), 256, 0, stream>>>(xb, wqT, MROWS, 512, 512, nullptr, nullptr, qb);
    gemm_bt<0><<<dim3(4, 64), 256, 0, stream>>>(xb, wkT, MROWS, 512, 512, nullptr, nullptr, kb);
    gemm_bt<1><<<dim3(4, 64), 256, 0, stream>>>(xb, wvT, MROWS, 512, 512, nullptr, nullptr, vtb);

    // attention
    attn_kernel<<<dim3(SEQ / 64, 16), 256, 0, stream>>>(qb, kb, vtb, ctx);

    // dense + residual -> t1 ; LN1 (in-place fp32 + bf16 copy)
    gemm_bt<2><<<dim3(4, 64), 256, 0, stream>>>(ctx, wdT, MROWS, 512, 512, dense_b, x, t1);
    ln_kernel<true><<<2048, 256, 0, stream>>>(t1, ln1_g, ln1_b, x1f, x1b);

    // FF
    gemm_bt<3><<<dim3(16, 64), 256, 0, stream>>>(x1b, f1T, MROWS, 2048, 512, ff1_b, nullptr, hb);
    gemm_bt<2><<<dim3(4, 64), 256, 0, stream>>>(hb, f2T, MROWS, 512, 2048, ff2_b, x1f, t1);

    // LN2 -> d_out
    ln_kernel<false><<<2048, 256, 0, stream>>>(t1, ln2_g, ln2_b, (float*)d_out, nullptr);
}